// Round 4
// baseline (86.132 us; speedup 1.0000x reference)
//
#include <hip/hip_runtime.h>

#define FLT_BIG 3.402823466e38f

// tie-break matches jax.lax.top_k: higher value wins; equal values -> lower index wins
static __device__ __forceinline__ bool better(float v1, int i1, float v2, int i2) {
  return (v1 > v2) || ((v1 == v2) && (i1 < i2));
}

// km[h][n][e] = mean_j x[(n*32+j)*256 + h*32+e]
__global__ void kmean_kernel(const float* __restrict__ x, float* __restrict__ km) {
  const int n = blockIdx.x;        // ball
  const int t = threadIdx.x;       // h*32+e
  const float* base = x + n * 32 * 256 + t;
  float acc = 0.f;
  #pragma unroll
  for (int j = 0; j < 32; ++j) acc += base[j * 256];
  const int h = t >> 5, e = t & 31;
  km[h * 8192 + n * 32 + e] = acc * (1.0f / 32.0f);
}

// Block = (head h, 128-query group qb, 128-ball half bh). Thread tile 8q x 8b.
// Emits per-half partial top2 {V1, V2, packed(I1,I2), E} to part[].
__global__ __launch_bounds__(256, 4) void select_kernel(const float* __restrict__ x,
                                                        const float* __restrict__ km,
                                                        float4* __restrict__ part) {
  __shared__ float smem[8192];     // 32 KB
  const int bid = blockIdx.x;
  const int h = bid >> 7;          // same-head blocks contiguous -> L2 reuse
  const int qb = (bid >> 1) & 63;  // 128-query group
  const int bh = bid & 1;          // ball half (128 balls)
  const int t = threadIdx.x;
  const int tq = t >> 4;           // 0..15 : rows 8*tq+i
  const int tb = t & 15;           // 0..15 : balls tb+16*j (local)

  float4* km4 = (float4*)smem;            // 128 balls x 8 chunks, chunk c at b*8 + (c ^ (b&7))
  float4* q4 = (float4*)(smem + 4096);    // 128 rows  x 8 chunks, chunk c at r*8 + (c ^ ((r>>3)&7))

  // ---- stage km half (coalesced global, swizzled LDS) ----
  {
    const float4* src = (const float4*)km + h * 2048 + bh * 1024;
    #pragma unroll
    for (int k = 0; k < 4; ++k) {
      const int idx = t + 256 * k;           // 0..1023
      const float4 v = src[idx];
      const int ball = idx >> 3, c = idx & 7;
      km4[ball * 8 + (c ^ (ball & 7))] = v;
    }
  }
  // ---- stage q rows (8 lanes per 128B row-slice, swizzled LDS) ----
  {
    #pragma unroll
    for (int k = 0; k < 4; ++k) {
      const int idx = t + 256 * k;           // 0..1023
      const int r = idx >> 3, c = idx & 7;
      const float4 v = *(const float4*)(x + (qb * 128 + r) * 256 + h * 32 + c * 4);
      q4[r * 8 + (c ^ ((r >> 3) & 7))] = v;
    }
  }
  __syncthreads();

  // ---- GEMM: acc[i][j] = q[8tq+i] . km[tb+16j] ----
  float acc[8][8];
  #pragma unroll
  for (int i = 0; i < 8; ++i)
    #pragma unroll
    for (int j = 0; j < 8; ++j) acc[i][j] = 0.f;

  const int swq = tq & 7, swb = tb & 7;
  #pragma unroll
  for (int s = 0; s < 8; ++s) {
    float4 qf[8];
    #pragma unroll
    for (int i = 0; i < 8; ++i) qf[i] = q4[(8 * tq + i) * 8 + (s ^ swq)];
    #pragma unroll
    for (int jj = 0; jj < 2; ++jj) {         // split kf to bound VGPR pressure
      float4 kf[4];
      #pragma unroll
      for (int j = 0; j < 4; ++j) kf[j] = km4[(tb + 16 * (4 * jj + j)) * 8 + (s ^ swb)];
      #pragma unroll
      for (int i = 0; i < 8; ++i)
        #pragma unroll
        for (int j = 0; j < 4; ++j) {
          float4 kv = kf[j];
          acc[i][4 * jj + j] = fmaf(qf[i].x, kv.x, acc[i][4 * jj + j]);
          acc[i][4 * jj + j] = fmaf(qf[i].y, kv.y, acc[i][4 * jj + j]);
          acc[i][4 * jj + j] = fmaf(qf[i].z, kv.z, acc[i][4 * jj + j]);
          acc[i][4 * jj + j] = fmaf(qf[i].w, kv.w, acc[i][4 * jj + j]);
        }
    }
  }

  // ---- merge phase: two row-halves, reusing smem ----
  float* c_v1 = smem;          // [64][17]
  float* c_v2 = smem + 1088;
  float* c_id = smem + 2176;
  float* c_es = smem + 3264;   // ends 4352
  float* s_v1 = smem + 4352;   // [64][2]
  float* s_v2 = smem + 4480;
  float* s_id = smem + 4608;
  float* s_es = smem + 4736;   // ends 4864

  #pragma unroll
  for (int half = 0; half < 2; ++half) {
    __syncthreads();   // previous phase's smem reads complete
    if ((tq >> 3) == half) {
      #pragma unroll
      for (int i = 0; i < 8; ++i) {
        const int rl = (8 * tq + i) & 63;
        float v[8];
        #pragma unroll
        for (int j = 0; j < 8; ++j) v[j] = acc[i][j] * 0.0625f;   // scale = 256^-0.5
        float v1 = v[0]; int i1 = tb;
        float v2 = -FLT_BIG; int i2 = 0;
        #pragma unroll
        for (int j = 1; j < 8; ++j) {
          const int idx = tb + 16 * j;
          if (better(v[j], idx, v1, i1)) { v2 = v1; i2 = i1; v1 = v[j]; i1 = idx; }
          else if (better(v[j], idx, v2, i2)) { v2 = v[j]; i2 = idx; }
        }
        float es = 0.f;
        #pragma unroll
        for (int j = 0; j < 8; ++j) es += __expf(v[j] - v1);
        c_v1[rl * 17 + tb] = v1;
        c_v2[rl * 17 + tb] = v2;
        c_id[rl * 17 + tb] = __int_as_float(i1 | (i2 << 8));
        c_es[rl * 17 + tb] = es;
      }
    }
    __syncthreads();
    if (t < 128) {   // level-1: unit (r = t>>1, g = t&1) merges chunks g*8 .. g*8+7
      const int r = t >> 1, g = t & 1;
      const int base = r * 17 + g * 8;
      float V1 = c_v1[base], V2 = c_v2[base], E = c_es[base];
      int id = __float_as_int(c_id[base]);
      int I1 = id & 255, I2 = (id >> 8) & 255;
      #pragma unroll
      for (int k = 1; k < 8; ++k) {
        const float nv1 = c_v1[base + k], nv2 = c_v2[base + k], nes = c_es[base + k];
        const int nid = __float_as_int(c_id[base + k]);
        const int ni1 = nid & 255, ni2 = (nid >> 8) & 255;
        const float m = fmaxf(V1, nv1);
        E = E * __expf(V1 - m) + nes * __expf(nv1 - m);
        if (better(nv1, ni1, V1, I1)) {
          if (better(V1, I1, nv2, ni2)) { V2 = V1; I2 = I1; } else { V2 = nv2; I2 = ni2; }
          V1 = nv1; I1 = ni1;
        } else if (better(nv1, ni1, V2, I2)) { V2 = nv1; I2 = ni1; }
      }
      s_v1[r * 2 + g] = V1; s_v2[r * 2 + g] = V2;
      s_id[r * 2 + g] = __int_as_float(I1 | (I2 << 8));
      s_es[r * 2 + g] = E;
    }
    __syncthreads();
    if (t < 64) {    // level-2: merge the 2 groups, emit partial (global ball indices)
      const int r = t;
      float V1 = s_v1[r * 2], V2 = s_v2[r * 2], E = s_es[r * 2];
      int id = __float_as_int(s_id[r * 2]);
      int I1 = id & 255, I2 = (id >> 8) & 255;
      {
        const float nv1 = s_v1[r * 2 + 1], nv2 = s_v2[r * 2 + 1], nes = s_es[r * 2 + 1];
        const int nid = __float_as_int(s_id[r * 2 + 1]);
        const int ni1 = nid & 255, ni2 = (nid >> 8) & 255;
        const float m = fmaxf(V1, nv1);
        E = E * __expf(V1 - m) + nes * __expf(nv1 - m);
        if (better(nv1, ni1, V1, I1)) {
          if (better(V1, I1, nv2, ni2)) { V2 = V1; I2 = I1; } else { V2 = nv2; I2 = ni2; }
          V1 = nv1; I1 = ni1;
        } else if (better(nv1, ni1, V2, I2)) { V2 = nv1; I2 = ni1; }
      }
      const int task = h * 8192 + qb * 128 + half * 64 + r;
      const int gI1 = I1 + bh * 128, gI2 = I2 + bh * 128;
      part[task * 2 + bh] = make_float4(V1, V2, __int_as_float(gI1 | (gI2 << 8)), E);
    }
  }
}

// combine the two 128-ball halves: global top2 + exact mask semantics
__global__ __launch_bounds__(256) void merge2_kernel(const float4* __restrict__ part,
                                                     int2* __restrict__ sel) {
  const int task = blockIdx.x * 256 + threadIdx.x;   // 0..65535
  const float4 a = part[task * 2 + 0];
  const float4 b = part[task * 2 + 1];
  float V1 = a.x, V2 = a.y, E0 = a.w;
  int id = __float_as_int(a.z);
  int I1 = id & 255, I2 = (id >> 8) & 255;
  const float bv1 = b.x, bv2 = b.y, E1 = b.w;
  const int bid_ = __float_as_int(b.z);
  const int bi1 = bid_ & 255, bi2 = (bid_ >> 8) & 255;

  const float m = fmaxf(V1, bv1);
  const float E = E0 * __expf(V1 - m) + E1 * __expf(bv1 - m);
  if (better(bv1, bi1, V1, I1)) {
    if (better(V1, I1, bv2, bi2)) { V2 = V1; I2 = I1; } else { V2 = bv2; I2 = bi2; }
    V1 = bv1; I1 = bi1;
  } else if (better(bv1, bi1, V2, I2)) { V2 = bv1; I2 = bi1; }

  const float topv1 = 1.0f / E;
  const float topv2 = __expf(V2 - V1) / E;
  const int o1 = (topv1 > 1e-10f) ? I1 : -1;
  const int o2 = (topv2 > 1e-10f) ? I2 : -1;
  sel[task] = make_int2(o1, o2);
}

// one wave per (h, q) task; 64 gathered keys from the 2 selected balls
__global__ __launch_bounds__(256) void attn_kernel(const float* __restrict__ x,
                                                   const int2* __restrict__ sel,
                                                   float* __restrict__ out) {
  __shared__ float p_lds[4 * 64];
  const int lane = threadIdx.x & 63;
  const int widx = threadIdx.x >> 6;
  const int task = blockIdx.x * 4 + widx;   // h*8192 + q
  const int h = task >> 13;
  const int q = task & 8191;

  const int2 sv = sel[task];
  const int iA = sv.x, iB = sv.y;
  const int bA = iA < 0 ? 0 : iA;
  const int bB = iB < 0 ? 0 : iB;

  const int ro = lane >> 3;          // row within 8-row group
  const int o = lane & 7;            // 16B chunk within row-slice
  const float4 qf = *(const float4*)(x + q * 256 + h * 32 + o * 4);

  // ---- key dots: 8 lanes per row (8 x 128B segments/instr) ----
  float dA[4], dB[4];
  #pragma unroll
  for (int i = 0; i < 4; ++i) {
    const float4 ka = *(const float4*)(x + (bA * 32 + i * 8 + ro) * 256 + h * 32 + o * 4);
    float a = qf.x * ka.x; a = fmaf(qf.y, ka.y, a); a = fmaf(qf.z, ka.z, a); a = fmaf(qf.w, ka.w, a);
    dA[i] = a;
    const float4 kb = *(const float4*)(x + (bB * 32 + i * 8 + ro) * 256 + h * 32 + o * 4);
    float bb = qf.x * kb.x; bb = fmaf(qf.y, kb.y, bb); bb = fmaf(qf.z, kb.z, bb); bb = fmaf(qf.w, kb.w, bb);
    dB[i] = bb;
  }
  #pragma unroll
  for (int m = 1; m <= 4; m <<= 1) {
    #pragma unroll
    for (int i = 0; i < 4; ++i) {
      dA[i] += __shfl_xor(dA[i], m);
      dB[i] += __shfl_xor(dB[i], m);
    }
  }

  // ---- masked softmax over 64 slots (values replicated 8x across o-lanes) ----
  float lA[4], lB[4];
  float mx = -FLT_BIG;
  #pragma unroll
  for (int i = 0; i < 4; ++i) {
    lA[i] = (iA >= 0) ? dA[i] * 0.0625f : -FLT_BIG;
    lB[i] = (iB >= 0) ? dB[i] * 0.0625f : -FLT_BIG;
    mx = fmaxf(mx, fmaxf(lA[i], lB[i]));
  }
  #pragma unroll
  for (int m = 8; m <= 32; m <<= 1) mx = fmaxf(mx, __shfl_xor(mx, m));
  float pA[4], pB[4], psum = 0.f;
  #pragma unroll
  for (int i = 0; i < 4; ++i) {
    pA[i] = __expf(lA[i] - mx);
    pB[i] = __expf(lB[i] - mx);
    psum += pA[i] + pB[i];
  }
  #pragma unroll
  for (int m = 8; m <= 32; m <<= 1) psum += __shfl_xor(psum, m);

  // ---- stash p to LDS (one writer lane per row) ----
  const int wbase = widx * 64;
  #pragma unroll
  for (int i = 0; i < 4; ++i) {
    if ((lane & 7) == i) {
      p_lds[wbase + 8 * i + ro] = pA[i];
      p_lds[wbase + 32 + 8 * i + ro] = pB[i];
    }
  }

  // ---- PV: lane (t2,e) sums 32 rows of its ball; V re-read transposed (L1-hot) ----
  const int t2 = lane >> 5;
  const int e = lane & 31;
  const int bP = t2 ? bB : bA;
  const float* vp = x + bP * 32 * 256 + h * 32 + e;
  float acc = 0.f;
  #pragma unroll
  for (int s = 0; s < 32; ++s) {
    float w = p_lds[wbase + t2 * 32 + s];   // broadcast read
    acc = fmaf(w, vp[s * 256], acc);
  }
  acc += __shfl_xor(acc, 32);
  if (lane < 32) out[q * 256 + h * 32 + e] = acc / psum;
}

extern "C" void kernel_launch(void* const* d_in, const int* in_sizes, int n_in,
                              void* d_out, int out_size, void* d_ws, size_t ws_size,
                              hipStream_t stream) {
  const float* x = (const float*)d_in[0];   // (8192, 256) fp32; pos (d_in[1]) is dead code
  float* km = (float*)d_ws;                                   // 256 KB
  float4* part = (float4*)((char*)d_ws + 262144);             // 2 MB (65536 tasks x 2 halves)
  int2* sel = (int2*)((char*)d_ws + 262144 + 2097152);        // 512 KB
  float* out = (float*)d_out;

  kmean_kernel<<<256, 256, 0, stream>>>(x, km);
  select_kernel<<<1024, 256, 0, stream>>>(x, km, part);
  merge2_kernel<<<256, 256, 0, stream>>>(part, sel);
  attn_kernel<<<16384, 256, 0, stream>>>(x, sel, out);
}

// Round 5
// 82.912 us; speedup vs baseline: 1.0388x; 1.0388x over previous
//
#include <hip/hip_runtime.h>

#define FLT_BIG 3.402823466e38f

// tie-break matches jax.lax.top_k: higher value wins; equal values -> lower index wins
static __device__ __forceinline__ bool better(float v1, int i1, float v2, int i2) {
  return (v1 > v2) || ((v1 == v2) && (i1 < i2));
}

// km[h][n][e] = mean_j x[(n*32+j)*256 + h*32+e]
__global__ void kmean_kernel(const float* __restrict__ x, float* __restrict__ km) {
  const int n = blockIdx.x;        // ball
  const int t = threadIdx.x;       // h*32+e
  const float* base = x + n * 32 * 256 + t;
  float acc = 0.f;
  #pragma unroll
  for (int j = 0; j < 32; ++j) acc += base[j * 256];
  const int h = t >> 5, e = t & 31;
  km[h * 8192 + n * 32 + e] = acc * (1.0f / 32.0f);
}

// Block = (head h, 128-query group qb, 128-ball half bh). Thread tile 8q x 8b.
// NOTE: no min-waves in launch_bounds — forcing 4 waves/EU capped VGPR at 64 and
// spilled the 64-float accumulator (41 MB scratch writes, round 4). ~110 VGPR
// lands in the 128 granule = 16 waves/CU = 4 blocks/CU anyway.
__global__ __launch_bounds__(256) void select_kernel(const float* __restrict__ x,
                                                     const float* __restrict__ km,
                                                     float4* __restrict__ part) {
  __shared__ float smem[8192];     // 32 KB
  const int bid = blockIdx.x;
  const int h = bid >> 7;          // same-head blocks contiguous -> L2 reuse
  const int qb = (bid >> 1) & 63;  // 128-query group
  const int bh = bid & 1;          // ball half (128 balls)
  const int t = threadIdx.x;
  const int tq = t >> 4;           // 0..15 : rows 8*tq+i
  const int tb = t & 15;           // 0..15 : balls tb+16*j (local)

  float4* km4 = (float4*)smem;            // 128 balls x 8 chunks, chunk c at b*8 + (c ^ (b&7))
  float4* q4 = (float4*)(smem + 4096);    // 128 rows  x 8 chunks, chunk c at r*8 + (c ^ ((r>>3)&7))

  // ---- stage km half (coalesced global, swizzled LDS) ----
  {
    const float4* src = (const float4*)km + h * 2048 + bh * 1024;
    #pragma unroll
    for (int k = 0; k < 4; ++k) {
      const int idx = t + 256 * k;           // 0..1023
      const float4 v = src[idx];
      const int ball = idx >> 3, c = idx & 7;
      km4[ball * 8 + (c ^ (ball & 7))] = v;
    }
  }
  // ---- stage q rows (8 lanes per 128B row-slice, swizzled LDS) ----
  {
    #pragma unroll
    for (int k = 0; k < 4; ++k) {
      const int idx = t + 256 * k;           // 0..1023
      const int r = idx >> 3, c = idx & 7;
      const float4 v = *(const float4*)(x + (qb * 128 + r) * 256 + h * 32 + c * 4);
      q4[r * 8 + (c ^ ((r >> 3) & 7))] = v;
    }
  }
  __syncthreads();

  // ---- GEMM: acc[i][j] = q[8tq+i] . km[tb+16j] ----
  float acc[8][8];
  #pragma unroll
  for (int i = 0; i < 8; ++i)
    #pragma unroll
    for (int j = 0; j < 8; ++j) acc[i][j] = 0.f;

  const int swq = tq & 7, swb = tb & 7;
  #pragma unroll
  for (int s = 0; s < 8; ++s) {
    float4 qf[8];
    #pragma unroll
    for (int i = 0; i < 8; ++i) qf[i] = q4[(8 * tq + i) * 8 + (s ^ swq)];
    #pragma unroll
    for (int jj = 0; jj < 2; ++jj) {         // split kf to bound VGPR pressure
      float4 kf[4];
      #pragma unroll
      for (int j = 0; j < 4; ++j) kf[j] = km4[(tb + 16 * (4 * jj + j)) * 8 + (s ^ swb)];
      #pragma unroll
      for (int i = 0; i < 8; ++i)
        #pragma unroll
        for (int j = 0; j < 4; ++j) {
          float4 kv = kf[j];
          acc[i][4 * jj + j] = fmaf(qf[i].x, kv.x, acc[i][4 * jj + j]);
          acc[i][4 * jj + j] = fmaf(qf[i].y, kv.y, acc[i][4 * jj + j]);
          acc[i][4 * jj + j] = fmaf(qf[i].z, kv.z, acc[i][4 * jj + j]);
          acc[i][4 * jj + j] = fmaf(qf[i].w, kv.w, acc[i][4 * jj + j]);
        }
    }
  }

  // ---- merge phase: two row-halves, reusing smem ----
  float* c_v1 = smem;          // [64][17]
  float* c_v2 = smem + 1088;
  float* c_id = smem + 2176;
  float* c_es = smem + 3264;   // ends 4352
  float* s_v1 = smem + 4352;   // [64][2]
  float* s_v2 = smem + 4480;
  float* s_id = smem + 4608;
  float* s_es = smem + 4736;   // ends 4864

  #pragma unroll
  for (int half = 0; half < 2; ++half) {
    __syncthreads();   // previous phase's smem reads complete
    if ((tq >> 3) == half) {
      #pragma unroll
      for (int i = 0; i < 8; ++i) {
        const int rl = (8 * tq + i) & 63;
        float v[8];
        #pragma unroll
        for (int j = 0; j < 8; ++j) v[j] = acc[i][j] * 0.0625f;   // scale = 256^-0.5
        float v1 = v[0]; int i1 = tb;
        float v2 = -FLT_BIG; int i2 = 0;
        #pragma unroll
        for (int j = 1; j < 8; ++j) {
          const int idx = tb + 16 * j;
          if (better(v[j], idx, v1, i1)) { v2 = v1; i2 = i1; v1 = v[j]; i1 = idx; }
          else if (better(v[j], idx, v2, i2)) { v2 = v[j]; i2 = idx; }
        }
        float es = 0.f;
        #pragma unroll
        for (int j = 0; j < 8; ++j) es += __expf(v[j] - v1);
        c_v1[rl * 17 + tb] = v1;
        c_v2[rl * 17 + tb] = v2;
        c_id[rl * 17 + tb] = __int_as_float(i1 | (i2 << 8));
        c_es[rl * 17 + tb] = es;
      }
    }
    __syncthreads();
    if (t < 128) {   // level-1: unit (r = t>>1, g = t&1) merges chunks g*8 .. g*8+7
      const int r = t >> 1, g = t & 1;
      const int base = r * 17 + g * 8;
      float V1 = c_v1[base], V2 = c_v2[base], E = c_es[base];
      int id = __float_as_int(c_id[base]);
      int I1 = id & 255, I2 = (id >> 8) & 255;
      #pragma unroll
      for (int k = 1; k < 8; ++k) {
        const float nv1 = c_v1[base + k], nv2 = c_v2[base + k], nes = c_es[base + k];
        const int nid = __float_as_int(c_id[base + k]);
        const int ni1 = nid & 255, ni2 = (nid >> 8) & 255;
        const float m = fmaxf(V1, nv1);
        E = E * __expf(V1 - m) + nes * __expf(nv1 - m);
        if (better(nv1, ni1, V1, I1)) {
          if (better(V1, I1, nv2, ni2)) { V2 = V1; I2 = I1; } else { V2 = nv2; I2 = ni2; }
          V1 = nv1; I1 = ni1;
        } else if (better(nv1, ni1, V2, I2)) { V2 = nv1; I2 = ni1; }
      }
      s_v1[r * 2 + g] = V1; s_v2[r * 2 + g] = V2;
      s_id[r * 2 + g] = __int_as_float(I1 | (I2 << 8));
      s_es[r * 2 + g] = E;
    }
    __syncthreads();
    if (t < 64) {    // level-2: merge the 2 groups, emit partial (global ball indices)
      const int r = t;
      float V1 = s_v1[r * 2], V2 = s_v2[r * 2], E = s_es[r * 2];
      int id = __float_as_int(s_id[r * 2]);
      int I1 = id & 255, I2 = (id >> 8) & 255;
      {
        const float nv1 = s_v1[r * 2 + 1], nv2 = s_v2[r * 2 + 1], nes = s_es[r * 2 + 1];
        const int nid = __float_as_int(s_id[r * 2 + 1]);
        const int ni1 = nid & 255, ni2 = (nid >> 8) & 255;
        const float m = fmaxf(V1, nv1);
        E = E * __expf(V1 - m) + nes * __expf(nv1 - m);
        if (better(nv1, ni1, V1, I1)) {
          if (better(V1, I1, nv2, ni2)) { V2 = V1; I2 = I1; } else { V2 = nv2; I2 = ni2; }
          V1 = nv1; I1 = ni1;
        } else if (better(nv1, ni1, V2, I2)) { V2 = nv1; I2 = ni1; }
      }
      const int task = h * 8192 + qb * 128 + half * 64 + r;
      const int gI1 = I1 + bh * 128, gI2 = I2 + bh * 128;
      part[task * 2 + bh] = make_float4(V1, V2, __int_as_float(gI1 | (gI2 << 8)), E);
    }
  }
}

// combine the two 128-ball halves: global top2 + exact mask semantics
__global__ __launch_bounds__(256) void merge2_kernel(const float4* __restrict__ part,
                                                     int2* __restrict__ sel) {
  const int task = blockIdx.x * 256 + threadIdx.x;   // 0..65535
  const float4 a = part[task * 2 + 0];
  const float4 b = part[task * 2 + 1];
  float V1 = a.x, V2 = a.y, E0 = a.w;
  int id = __float_as_int(a.z);
  int I1 = id & 255, I2 = (id >> 8) & 255;
  const float bv1 = b.x, bv2 = b.y, E1 = b.w;
  const int bid_ = __float_as_int(b.z);
  const int bi1 = bid_ & 255, bi2 = (bid_ >> 8) & 255;

  const float m = fmaxf(V1, bv1);
  const float E = E0 * __expf(V1 - m) + E1 * __expf(bv1 - m);
  if (better(bv1, bi1, V1, I1)) {
    if (better(V1, I1, bv2, bi2)) { V2 = V1; I2 = I1; } else { V2 = bv2; I2 = bi2; }
    V1 = bv1; I1 = bi1;
  } else if (better(bv1, bi1, V2, I2)) { V2 = bv1; I2 = bi1; }

  const float topv1 = 1.0f / E;
  const float topv2 = __expf(V2 - V1) / E;
  const int o1 = (topv1 > 1e-10f) ? I1 : -1;
  const int o2 = (topv2 > 1e-10f) ? I2 : -1;
  sel[task] = make_int2(o1, o2);
}

// one wave per (h, q) task; 64 gathered keys from the 2 selected balls
__global__ __launch_bounds__(256) void attn_kernel(const float* __restrict__ x,
                                                   const int2* __restrict__ sel,
                                                   float* __restrict__ out) {
  __shared__ float p_lds[4 * 64];
  const int lane = threadIdx.x & 63;
  const int widx = threadIdx.x >> 6;
  const int task = blockIdx.x * 4 + widx;   // h*8192 + q
  const int h = task >> 13;
  const int q = task & 8191;

  const int2 sv = sel[task];
  const int iA = sv.x, iB = sv.y;
  const int bA = iA < 0 ? 0 : iA;
  const int bB = iB < 0 ? 0 : iB;

  const int ro = lane >> 3;          // row within 8-row group
  const int o = lane & 7;            // 16B chunk within row-slice
  const float4 qf = *(const float4*)(x + q * 256 + h * 32 + o * 4);

  // ---- key dots: 8 lanes per row (8 x 128B segments/instr) ----
  float dA[4], dB[4];
  #pragma unroll
  for (int i = 0; i < 4; ++i) {
    const float4 ka = *(const float4*)(x + (bA * 32 + i * 8 + ro) * 256 + h * 32 + o * 4);
    float a = qf.x * ka.x; a = fmaf(qf.y, ka.y, a); a = fmaf(qf.z, ka.z, a); a = fmaf(qf.w, ka.w, a);
    dA[i] = a;
    const float4 kb = *(const float4*)(x + (bB * 32 + i * 8 + ro) * 256 + h * 32 + o * 4);
    float bb = qf.x * kb.x; bb = fmaf(qf.y, kb.y, bb); bb = fmaf(qf.z, kb.z, bb); bb = fmaf(qf.w, kb.w, bb);
    dB[i] = bb;
  }
  #pragma unroll
  for (int m = 1; m <= 4; m <<= 1) {
    #pragma unroll
    for (int i = 0; i < 4; ++i) {
      dA[i] += __shfl_xor(dA[i], m);
      dB[i] += __shfl_xor(dB[i], m);
    }
  }

  // ---- masked softmax over 64 slots (values replicated 8x across o-lanes) ----
  float lA[4], lB[4];
  float mx = -FLT_BIG;
  #pragma unroll
  for (int i = 0; i < 4; ++i) {
    lA[i] = (iA >= 0) ? dA[i] * 0.0625f : -FLT_BIG;
    lB[i] = (iB >= 0) ? dB[i] * 0.0625f : -FLT_BIG;
    mx = fmaxf(mx, fmaxf(lA[i], lB[i]));
  }
  #pragma unroll
  for (int m = 8; m <= 32; m <<= 1) mx = fmaxf(mx, __shfl_xor(mx, m));
  float pA[4], pB[4], psum = 0.f;
  #pragma unroll
  for (int i = 0; i < 4; ++i) {
    pA[i] = __expf(lA[i] - mx);
    pB[i] = __expf(lB[i] - mx);
    psum += pA[i] + pB[i];
  }
  #pragma unroll
  for (int m = 8; m <= 32; m <<= 1) psum += __shfl_xor(psum, m);

  // ---- stash p to LDS (one writer lane per row) ----
  const int wbase = widx * 64;
  #pragma unroll
  for (int i = 0; i < 4; ++i) {
    if ((lane & 7) == i) {
      p_lds[wbase + 8 * i + ro] = pA[i];
      p_lds[wbase + 32 + 8 * i + ro] = pB[i];
    }
  }

  // ---- PV: lane (t2,e) sums 32 rows of its ball; V re-read transposed (L1-hot) ----
  const int t2 = lane >> 5;
  const int e = lane & 31;
  const int bP = t2 ? bB : bA;
  const float* vp = x + bP * 32 * 256 + h * 32 + e;
  float acc = 0.f;
  #pragma unroll
  for (int s = 0; s < 32; ++s) {
    float w = p_lds[wbase + t2 * 32 + s];   // broadcast read
    acc = fmaf(w, vp[s * 256], acc);
  }
  acc += __shfl_xor(acc, 32);
  if (lane < 32) out[q * 256 + h * 32 + e] = acc / psum;
}

extern "C" void kernel_launch(void* const* d_in, const int* in_sizes, int n_in,
                              void* d_out, int out_size, void* d_ws, size_t ws_size,
                              hipStream_t stream) {
  const float* x = (const float*)d_in[0];   // (8192, 256) fp32; pos (d_in[1]) is dead code
  float* km = (float*)d_ws;                                   // 256 KB
  float4* part = (float4*)((char*)d_ws + 262144);             // 2 MB (65536 tasks x 2 halves)
  int2* sel = (int2*)((char*)d_ws + 262144 + 2097152);        // 512 KB
  float* out = (float*)d_out;

  kmean_kernel<<<256, 256, 0, stream>>>(x, km);
  select_kernel<<<1024, 256, 0, stream>>>(x, km, part);
  merge2_kernel<<<256, 256, 0, stream>>>(part, sel);
  attn_kernel<<<16384, 256, 0, stream>>>(x, sel, out);
}